// Round 1
// baseline (6618.224 us; speedup 1.0000x reference)
//
#include <hip/hip_runtime.h>

#define N_NODES 250000
#define N_EDGES 4000000
#define HID 32
#define NN 50
#define NF 3
#define OUT_COLS (NN + NF)   // 53

__device__ __forceinline__ float softplus_f(float v) {
    // matches jax.nn.softplus = log1p(exp(v)) with stable form
    return fmaxf(v, 0.0f) + log1pf(expf(-fabsf(v)));
}

__global__ __launch_bounds__(256) void edge_mlp_kernel(
    const float* __restrict__ x, const int* __restrict__ ei,
    const float* __restrict__ ea,
    const float* __restrict__ W1, const float* __restrict__ b1,
    const float* __restrict__ W2, const float* __restrict__ b2,
    float* __restrict__ agg)
{
    int e = blockIdx.x * 256 + threadIdx.x;
    if (e >= N_EDGES) return;
    int r = ei[e];
    int c = ei[N_EDGES + e];
    float4 xr = *(const float4*)(x + 4 * (size_t)r);
    float4 xc = *(const float4*)(x + 4 * (size_t)c);
    float in[9] = {xr.x, xr.y, xr.z, xr.w, xc.x, xc.y, xc.z, xc.w, ea[e]};

    float h[HID];
    #pragma unroll
    for (int k = 0; k < HID; k++) {
        float a = b1[k];
        #pragma unroll
        for (int i = 0; i < 9; i++) a = fmaf(in[i], W1[i * HID + k], a);
        h[k] = fmaxf(a, 0.0f);
    }

    float* dst = agg + (size_t)r * HID;
    #pragma unroll
    for (int j = 0; j < HID; j++) {
        float a = b2[j];
        #pragma unroll
        for (int k = 0; k < HID; k++) a = fmaf(h[k], W2[k * HID + j], a);
        atomicAdd(dst + j, a);
    }
}

__global__ __launch_bounds__(256) void node_kernel(
    const float* __restrict__ x, const float* __restrict__ agg,
    const float* __restrict__ Wc, const float* __restrict__ bc,
    const float* __restrict__ Wmu, const float* __restrict__ bmu,
    const float* __restrict__ Wsig, const float* __restrict__ bsig,
    const float* __restrict__ high,
    float* __restrict__ conc, float* __restrict__ sum_out,
    float* __restrict__ out)
{
    int n = blockIdx.x * 256 + threadIdx.x;
    float c_val = 0.0f;
    if (n < N_NODES) {
        float v[36];
        float4 xv = *(const float4*)(x + 4 * (size_t)n);
        v[0] = xv.x; v[1] = xv.y; v[2] = xv.z; v[3] = xv.w;
        const float4* ag = (const float4*)(agg + (size_t)n * HID);
        #pragma unroll
        for (int q = 0; q < 8; q++) {
            float4 t = ag[q];
            v[4 + 4 * q] = t.x; v[5 + 4 * q] = t.y;
            v[6 + 4 * q] = t.z; v[7 + 4 * q] = t.w;
        }
        float zc = bc[0];
        #pragma unroll
        for (int d = 0; d < 36; d++) zc = fmaf(v[d], Wc[d], zc);
        c_val = softplus_f(zc + 1e-10f);
        conc[n] = c_val;

        int g = n / NN;
        int i = n - g * NN;
        if (i >= NN - NF) {
            float zm = bmu[0], zs = bsig[0];
            #pragma unroll
            for (int d = 0; d < 36; d++) {
                zm = fmaf(v[d], Wmu[d], zm);
                zs = fmaf(v[d], Wsig[d], zs);
            }
            float alpha = softplus_f(zm + 1e-20f) + 1e-20f;
            float beta  = softplus_f(zs + 1e-20f) + 1e-20f;
            int k = i - (NN - NF);
            out[(size_t)g * OUT_COLS + NN + k] = alpha / (alpha + beta) * high[k];
        }
    }

    // block reduction of c_val -> one atomic per block
    __shared__ float wave_sums[4];
    float s = c_val;
    #pragma unroll
    for (int off = 32; off > 0; off >>= 1) s += __shfl_down(s, off, 64);
    int lane = threadIdx.x & 63;
    int wid  = threadIdx.x >> 6;
    if (lane == 0) wave_sums[wid] = s;
    __syncthreads();
    if (threadIdx.x == 0) {
        float t = wave_sums[0] + wave_sums[1] + wave_sums[2] + wave_sums[3];
        atomicAdd(sum_out, t);
    }
}

__global__ __launch_bounds__(256) void div_kernel(
    const float* __restrict__ conc, const float* __restrict__ sum_in,
    float* __restrict__ out)
{
    int n = blockIdx.x * 256 + threadIdx.x;
    if (n >= N_NODES) return;
    float inv = 1.0f / (*sum_in + 1e-20f);
    int g = n / NN;
    int i = n - g * NN;
    out[(size_t)g * OUT_COLS + i] = conc[n] * inv;
}

extern "C" void kernel_launch(void* const* d_in, const int* in_sizes, int n_in,
                              void* d_out, int out_size, void* d_ws, size_t ws_size,
                              hipStream_t stream)
{
    const float* x    = (const float*)d_in[0];
    const int*   ei   = (const int*)d_in[1];
    const float* ea   = (const float*)d_in[2];
    const float* high = (const float*)d_in[3];
    const float* W1   = (const float*)d_in[4];
    const float* b1   = (const float*)d_in[5];
    const float* W2   = (const float*)d_in[6];
    const float* b2   = (const float*)d_in[7];
    const float* Wc   = (const float*)d_in[8];
    const float* bc   = (const float*)d_in[9];
    const float* Wmu  = (const float*)d_in[10];
    const float* bmu  = (const float*)d_in[11];
    const float* Wsig = (const float*)d_in[12];
    const float* bsig = (const float*)d_in[13];
    float* out = (float*)d_out;

    char* ws = (char*)d_ws;
    float* agg  = (float*)ws;                    // 250000*32 floats = 32,000,000 B
    float* conc = (float*)(ws + 32000000);       // 250000 floats   =  1,000,000 B
    float* ssum = (float*)(ws + 33000000);       // 1 float

    hipMemsetAsync(agg, 0, 32000000, stream);
    hipMemsetAsync(ssum, 0, 4, stream);

    edge_mlp_kernel<<<(N_EDGES + 255) / 256, 256, 0, stream>>>(
        x, ei, ea, W1, b1, W2, b2, agg);
    node_kernel<<<(N_NODES + 255) / 256, 256, 0, stream>>>(
        x, agg, Wc, bc, Wmu, bmu, Wsig, bsig, high, conc, ssum, out);
    div_kernel<<<(N_NODES + 255) / 256, 256, 0, stream>>>(conc, ssum, out);
}

// Round 2
// 1023.466 us; speedup vs baseline: 6.4665x; 6.4665x over previous
//
#include <hip/hip_runtime.h>

#define N_NODES 250000
#define N_EDGES 4000000
#define HID 32
#define NN 50
#define NF 3
#define OUT_COLS (NN + NF)   // 53
#define SCAN_TILE 2048
#define SCAN_NBLK ((N_NODES + SCAN_TILE - 1) / SCAN_TILE)  // 123

__device__ __forceinline__ float softplus_f(float v) {
    return fmaxf(v, 0.0f) + log1pf(expf(-fabsf(v)));
}

// ---- Phase 1: histogram of edge rows ----
__global__ __launch_bounds__(256) void hist_kernel(
    const int* __restrict__ ei, int* __restrict__ counts)
{
    int e = blockIdx.x * 256 + threadIdx.x;   // grid sized exactly
    atomicAdd(&counts[ei[e]], 1);
}

// ---- Phase 2a: per-tile sums ----
__global__ __launch_bounds__(256) void scan_a_kernel(
    const int* __restrict__ counts, int* __restrict__ bsum)
{
    int b = blockIdx.x, t = threadIdx.x;
    int base = b * SCAN_TILE + t * 8;
    int s = 0;
    #pragma unroll
    for (int j = 0; j < 8; j++) {
        int i = base + j;
        if (i < N_NODES) s += counts[i];
    }
    __shared__ int wsum[4];
    #pragma unroll
    for (int off = 32; off > 0; off >>= 1) s += __shfl_down(s, off, 64);
    int lane = t & 63, wid = t >> 6;
    if (lane == 0) wsum[wid] = s;
    __syncthreads();
    if (t == 0) bsum[b] = wsum[0] + wsum[1] + wsum[2] + wsum[3];
}

// ---- Phase 2b: exclusive scan of tile sums (single block) ----
__global__ __launch_bounds__(256) void scan_b_kernel(int* __restrict__ bsum)
{
    int t = threadIdx.x;
    __shared__ int sh[256];
    int v = (t < SCAN_NBLK) ? bsum[t] : 0;
    sh[t] = v;
    __syncthreads();
    #pragma unroll
    for (int off = 1; off < 256; off <<= 1) {
        int a = (t >= off) ? sh[t - off] : 0;
        __syncthreads();
        sh[t] += a;
        __syncthreads();
    }
    if (t < SCAN_NBLK) bsum[t] = sh[t] - v;   // exclusive
}

// ---- Phase 2c: full exclusive scan -> offs, cursor ----
__global__ __launch_bounds__(256) void scan_c_kernel(
    const int* __restrict__ counts, const int* __restrict__ bsum,
    int* __restrict__ offs, int* __restrict__ cursor)
{
    int b = blockIdx.x, t = threadIdx.x;
    int base = b * SCAN_TILE + t * 8;
    int cnt[8];
    int s = 0;
    #pragma unroll
    for (int j = 0; j < 8; j++) {
        int i = base + j;
        cnt[j] = (i < N_NODES) ? counts[i] : 0;
        s += cnt[j];
    }
    __shared__ int sh[256];
    sh[t] = s;
    __syncthreads();
    #pragma unroll
    for (int off = 1; off < 256; off <<= 1) {
        int a = (t >= off) ? sh[t - off] : 0;
        __syncthreads();
        sh[t] += a;
        __syncthreads();
    }
    int running = bsum[b] + (sh[t] - s);   // block base + thread-exclusive
    #pragma unroll
    for (int j = 0; j < 8; j++) {
        int i = base + j;
        if (i < N_NODES) {
            offs[i] = running;
            cursor[i] = running;
            running += cnt[j];
        }
    }
}

// ---- Phase 3: scatter (col, edge_attr) into CSR order ----
__global__ __launch_bounds__(256) void scatter_kernel(
    const int* __restrict__ ei, const float* __restrict__ ea,
    int* __restrict__ cursor, int2* __restrict__ sorted)
{
    int e = blockIdx.x * 256 + threadIdx.x;   // grid sized exactly
    int r = ei[e];
    int c = ei[N_EDGES + e];
    int pos = atomicAdd(&cursor[r], 1);
    int2 v;
    v.x = c;
    v.y = __float_as_int(ea[e]);
    sorted[pos] = v;
}

// ---- Phase 4: per-node gather + edge MLP recompute + heads (fused) ----
__global__ __launch_bounds__(256) void gather_kernel(
    const float* __restrict__ x, const int* __restrict__ offs,
    const int* __restrict__ counts, const int2* __restrict__ sorted,
    const float* __restrict__ W1, const float* __restrict__ b1,
    const float* __restrict__ W2, const float* __restrict__ b2,
    const float* __restrict__ Wc, const float* __restrict__ bc,
    const float* __restrict__ Wmu, const float* __restrict__ bmu,
    const float* __restrict__ Wsig, const float* __restrict__ bsig,
    const float* __restrict__ high,
    float* __restrict__ conc, float* __restrict__ sum_out,
    float* __restrict__ out)
{
    int n = blockIdx.x * 256 + threadIdx.x;
    float c_val = 0.0f;
    if (n < N_NODES) {
        int beg = offs[n];
        int deg = counts[n];
        int end = beg + deg;
        float4 xr = *(const float4*)(x + 4 * (size_t)n);

        float acc[HID];
        #pragma unroll
        for (int j = 0; j < HID; j++) acc[j] = (float)deg * b2[j];

        for (int p = beg; p < end; ++p) {
            int2 ce = sorted[p];
            float4 xc = *(const float4*)(x + 4 * (size_t)ce.x);
            float eav = __int_as_float(ce.y);
            float h[HID];
            #pragma unroll
            for (int k = 0; k < HID; k++) {
                float a = b1[k];
                a = fmaf(xr.x, W1[0 * HID + k], a);
                a = fmaf(xr.y, W1[1 * HID + k], a);
                a = fmaf(xr.z, W1[2 * HID + k], a);
                a = fmaf(xr.w, W1[3 * HID + k], a);
                a = fmaf(xc.x, W1[4 * HID + k], a);
                a = fmaf(xc.y, W1[5 * HID + k], a);
                a = fmaf(xc.z, W1[6 * HID + k], a);
                a = fmaf(xc.w, W1[7 * HID + k], a);
                a = fmaf(eav,  W1[8 * HID + k], a);
                h[k] = fmaxf(a, 0.0f);
            }
            #pragma unroll
            for (int k = 0; k < HID; k++) {
                float hk = h[k];
                #pragma unroll
                for (int j = 0; j < HID; j++)
                    acc[j] = fmaf(hk, W2[k * HID + j], acc[j]);
            }
        }

        // heads: v = [x[n], agg[n]]
        float zc = bc[0];
        zc = fmaf(xr.x, Wc[0], zc);
        zc = fmaf(xr.y, Wc[1], zc);
        zc = fmaf(xr.z, Wc[2], zc);
        zc = fmaf(xr.w, Wc[3], zc);
        #pragma unroll
        for (int j = 0; j < HID; j++) zc = fmaf(acc[j], Wc[4 + j], zc);
        c_val = softplus_f(zc + 1e-10f);
        conc[n] = c_val;

        int g = n / NN;
        int i = n - g * NN;
        if (i >= NN - NF) {
            float zm = bmu[0], zs = bsig[0];
            zm = fmaf(xr.x, Wmu[0], zm);   zs = fmaf(xr.x, Wsig[0], zs);
            zm = fmaf(xr.y, Wmu[1], zm);   zs = fmaf(xr.y, Wsig[1], zs);
            zm = fmaf(xr.z, Wmu[2], zm);   zs = fmaf(xr.z, Wsig[2], zs);
            zm = fmaf(xr.w, Wmu[3], zm);   zs = fmaf(xr.w, Wsig[3], zs);
            #pragma unroll
            for (int j = 0; j < HID; j++) {
                zm = fmaf(acc[j], Wmu[4 + j], zm);
                zs = fmaf(acc[j], Wsig[4 + j], zs);
            }
            float alpha = softplus_f(zm + 1e-20f) + 1e-20f;
            float beta  = softplus_f(zs + 1e-20f) + 1e-20f;
            int k = i - (NN - NF);
            out[(size_t)g * OUT_COLS + NN + k] = alpha / (alpha + beta) * high[k];
        }
    }

    __shared__ float wave_sums[4];
    float s = c_val;
    #pragma unroll
    for (int off = 32; off > 0; off >>= 1) s += __shfl_down(s, off, 64);
    int lane = threadIdx.x & 63;
    int wid  = threadIdx.x >> 6;
    if (lane == 0) wave_sums[wid] = s;
    __syncthreads();
    if (threadIdx.x == 0) {
        float t = wave_sums[0] + wave_sums[1] + wave_sums[2] + wave_sums[3];
        atomicAdd(sum_out, t);
    }
}

__global__ __launch_bounds__(256) void div_kernel(
    const float* __restrict__ conc, const float* __restrict__ sum_in,
    float* __restrict__ out)
{
    int n = blockIdx.x * 256 + threadIdx.x;
    if (n >= N_NODES) return;
    float inv = 1.0f / (*sum_in + 1e-20f);
    int g = n / NN;
    int i = n - g * NN;
    out[(size_t)g * OUT_COLS + i] = conc[n] * inv;
}

extern "C" void kernel_launch(void* const* d_in, const int* in_sizes, int n_in,
                              void* d_out, int out_size, void* d_ws, size_t ws_size,
                              hipStream_t stream)
{
    const float* x    = (const float*)d_in[0];
    const int*   ei   = (const int*)d_in[1];
    const float* ea   = (const float*)d_in[2];
    const float* high = (const float*)d_in[3];
    const float* W1   = (const float*)d_in[4];
    const float* b1   = (const float*)d_in[5];
    const float* W2   = (const float*)d_in[6];
    const float* b2   = (const float*)d_in[7];
    const float* Wc   = (const float*)d_in[8];
    const float* bc   = (const float*)d_in[9];
    const float* Wmu  = (const float*)d_in[10];
    const float* bmu  = (const float*)d_in[11];
    const float* Wsig = (const float*)d_in[12];
    const float* bsig = (const float*)d_in[13];
    float* out = (float*)d_out;

    char* ws = (char*)d_ws;
    int2*  sorted = (int2*)ws;                      // 32,000,000 B
    int*   counts = (int*)(ws + 32000000);          //  1,000,000 B
    int*   offs   = (int*)(ws + 33000000);          //  1,000,000 B
    int*   cursor = (int*)(ws + 34000000);          //  1,000,000 B
    int*   bsum   = (int*)(ws + 35000000);          //      4,096 B
    float* conc   = (float*)(ws + 35004096);        //  1,000,000 B
    float* ssum   = (float*)(ws + 36004096);        //          4 B

    hipMemsetAsync(counts, 0, 1000000, stream);
    hipMemsetAsync(ssum, 0, 4, stream);

    hist_kernel<<<N_EDGES / 256, 256, 0, stream>>>(ei, counts);
    scan_a_kernel<<<SCAN_NBLK, 256, 0, stream>>>(counts, bsum);
    scan_b_kernel<<<1, 256, 0, stream>>>(bsum);
    scan_c_kernel<<<SCAN_NBLK, 256, 0, stream>>>(counts, bsum, offs, cursor);
    scatter_kernel<<<N_EDGES / 256, 256, 0, stream>>>(ei, ea, cursor, sorted);
    gather_kernel<<<(N_NODES + 255) / 256, 256, 0, stream>>>(
        x, offs, counts, sorted, W1, b1, W2, b2, Wc, bc, Wmu, bmu, Wsig, bsig,
        high, conc, ssum, out);
    div_kernel<<<(N_NODES + 255) / 256, 256, 0, stream>>>(conc, ssum, out);
}

// Round 3
// 998.117 us; speedup vs baseline: 6.6307x; 1.0254x over previous
//
#include <hip/hip_runtime.h>

#define N_NODES 250000
#define N_EDGES 4000000
#define HID 32
#define NN 50
#define NF 3
#define OUT_COLS (NN + NF)   // 53
#define SCAN_TILE 2048
#define SCAN_NBLK ((N_NODES + SCAN_TILE - 1) / SCAN_TILE)  // 123

typedef float float2v __attribute__((ext_vector_type(2)));

__device__ __forceinline__ float softplus_f(float v) {
    return fmaxf(v, 0.0f) + log1pf(expf(-fabsf(v)));
}

__device__ __forceinline__ float2v pk_fma(float a, float2v b, float2v c) {
    float2v av = {a, a};
    return __builtin_elementwise_fma(av, b, c);
}

// ---- Phase 1: histogram of edge rows (4 edges/thread) ----
__global__ __launch_bounds__(256) void hist_kernel(
    const int* __restrict__ ei, int* __restrict__ counts)
{
    int t = blockIdx.x * 256 + threadIdx.x;
    if (t >= N_EDGES / 4) return;
    int4 r4 = ((const int4*)ei)[t];
    atomicAdd(&counts[r4.x], 1);
    atomicAdd(&counts[r4.y], 1);
    atomicAdd(&counts[r4.z], 1);
    atomicAdd(&counts[r4.w], 1);
}

// ---- Phase 2a: per-tile sums ----
__global__ __launch_bounds__(256) void scan_a_kernel(
    const int* __restrict__ counts, int* __restrict__ bsum)
{
    int b = blockIdx.x, t = threadIdx.x;
    int base = b * SCAN_TILE + t * 8;
    int s = 0;
    #pragma unroll
    for (int j = 0; j < 8; j++) {
        int i = base + j;
        if (i < N_NODES) s += counts[i];
    }
    __shared__ int wsum[4];
    #pragma unroll
    for (int off = 32; off > 0; off >>= 1) s += __shfl_down(s, off, 64);
    int lane = t & 63, wid = t >> 6;
    if (lane == 0) wsum[wid] = s;
    __syncthreads();
    if (t == 0) bsum[b] = wsum[0] + wsum[1] + wsum[2] + wsum[3];
}

// ---- Phase 2b: exclusive scan of tile sums (single block) ----
__global__ __launch_bounds__(256) void scan_b_kernel(int* __restrict__ bsum)
{
    int t = threadIdx.x;
    __shared__ int sh[256];
    int v = (t < SCAN_NBLK) ? bsum[t] : 0;
    sh[t] = v;
    __syncthreads();
    #pragma unroll
    for (int off = 1; off < 256; off <<= 1) {
        int a = (t >= off) ? sh[t - off] : 0;
        __syncthreads();
        sh[t] += a;
        __syncthreads();
    }
    if (t < SCAN_NBLK) bsum[t] = sh[t] - v;   // exclusive
}

// ---- Phase 2c: full exclusive scan -> offs, cursor ----
__global__ __launch_bounds__(256) void scan_c_kernel(
    const int* __restrict__ counts, const int* __restrict__ bsum,
    int* __restrict__ offs, int* __restrict__ cursor)
{
    int b = blockIdx.x, t = threadIdx.x;
    int base = b * SCAN_TILE + t * 8;
    int cnt[8];
    int s = 0;
    #pragma unroll
    for (int j = 0; j < 8; j++) {
        int i = base + j;
        cnt[j] = (i < N_NODES) ? counts[i] : 0;
        s += cnt[j];
    }
    __shared__ int sh[256];
    sh[t] = s;
    __syncthreads();
    #pragma unroll
    for (int off = 1; off < 256; off <<= 1) {
        int a = (t >= off) ? sh[t - off] : 0;
        __syncthreads();
        sh[t] += a;
        __syncthreads();
    }
    int running = bsum[b] + (sh[t] - s);
    #pragma unroll
    for (int j = 0; j < 8; j++) {
        int i = base + j;
        if (i < N_NODES) {
            offs[i] = running;
            cursor[i] = running;
            running += cnt[j];
        }
    }
}

// ---- Phase 3: scatter (col, edge_attr) into CSR order (4 edges/thread) ----
__global__ __launch_bounds__(256) void scatter_kernel(
    const int* __restrict__ ei, const float* __restrict__ ea,
    int* __restrict__ cursor, int2* __restrict__ sorted)
{
    int t = blockIdx.x * 256 + threadIdx.x;
    if (t >= N_EDGES / 4) return;
    int4 r4 = ((const int4*)ei)[t];
    int4 c4 = ((const int4*)(ei + N_EDGES))[t];
    float4 e4 = ((const float4*)ea)[t];
    int pos;
    pos = atomicAdd(&cursor[r4.x], 1); sorted[pos] = make_int2(c4.x, __float_as_int(e4.x));
    pos = atomicAdd(&cursor[r4.y], 1); sorted[pos] = make_int2(c4.y, __float_as_int(e4.y));
    pos = atomicAdd(&cursor[r4.z], 1); sorted[pos] = make_int2(c4.z, __float_as_int(e4.z));
    pos = atomicAdd(&cursor[r4.w], 1); sorted[pos] = make_int2(c4.w, __float_as_int(e4.w));
}

// ---- Phase 4: gather, 4 lanes per node, packed-f32 MLP, fused heads ----
__global__ __launch_bounds__(256) void gather_kernel(
    const float* __restrict__ x, const int* __restrict__ offs,
    const int* __restrict__ counts, const int2* __restrict__ sorted,
    const float* __restrict__ W1, const float* __restrict__ b1,
    const float* __restrict__ W2, const float* __restrict__ b2,
    const float* __restrict__ Wc, const float* __restrict__ bc,
    const float* __restrict__ Wmu, const float* __restrict__ bmu,
    const float* __restrict__ Wsig, const float* __restrict__ bsig,
    const float* __restrict__ high,
    float* __restrict__ conc, float* __restrict__ sum_out,
    float* __restrict__ out)
{
    int t = blockIdx.x * 256 + threadIdx.x;
    int n = t >> 2;            // node id (4 consecutive lanes per node)
    int slice = t & 3;
    bool valid = n < N_NODES;
    int nn = valid ? n : 0;

    int beg = offs[nn];
    int deg = valid ? counts[nn] : 0;
    int end = beg + deg;

    float4 xr = *(const float4*)(x + 4 * (size_t)nn);

    const float2v* W1v = (const float2v*)W1;   // [9][16]
    const float2v* W2v = (const float2v*)W2;   // [32][16]
    const float2v* b1v = (const float2v*)b1;
    const float2v* b2v = (const float2v*)b2;

    // this slice handles edges beg+slice, beg+slice+4, ...
    int cnt = (deg > slice) ? ((deg - slice + 3) >> 2) : 0;
    float2v acc2[16];
    float fc = (float)cnt;
    #pragma unroll
    for (int j2 = 0; j2 < 16; j2++) {
        float2v bb = b2v[j2];
        float2v z = {fc * bb.x, fc * bb.y};
        acc2[j2] = z;
    }

    int p = beg + slice;
    bool have = p < end;
    int2 ce = make_int2(0, 0);
    float4 xc = make_float4(0.f, 0.f, 0.f, 0.f);
    if (have) {
        ce = sorted[p];
        xc = *(const float4*)(x + 4 * (size_t)ce.x);
    }
    while (have) {
        int pn = p + 4;
        bool have_n = pn < end;
        int2 ce_n = make_int2(0, 0);
        float4 xc_n = make_float4(0.f, 0.f, 0.f, 0.f);
        if (have_n) {
            ce_n = sorted[pn];
            xc_n = *(const float4*)(x + 4 * (size_t)ce_n.x);
        }
        float eav = __int_as_float(ce.y);
        #pragma unroll
        for (int k2 = 0; k2 < 16; k2++) {
            float2v a = b1v[k2];
            a = pk_fma(xr.x, W1v[0 * 16 + k2], a);
            a = pk_fma(xr.y, W1v[1 * 16 + k2], a);
            a = pk_fma(xr.z, W1v[2 * 16 + k2], a);
            a = pk_fma(xr.w, W1v[3 * 16 + k2], a);
            a = pk_fma(xc.x, W1v[4 * 16 + k2], a);
            a = pk_fma(xc.y, W1v[5 * 16 + k2], a);
            a = pk_fma(xc.z, W1v[6 * 16 + k2], a);
            a = pk_fma(xc.w, W1v[7 * 16 + k2], a);
            a = pk_fma(eav,  W1v[8 * 16 + k2], a);
            float h0 = fmaxf(a.x, 0.0f);
            float h1 = fmaxf(a.y, 0.0f);
            #pragma unroll
            for (int j2 = 0; j2 < 16; j2++) {
                acc2[j2] = pk_fma(h0, W2v[(2 * k2) * 16 + j2], acc2[j2]);
                acc2[j2] = pk_fma(h1, W2v[(2 * k2 + 1) * 16 + j2], acc2[j2]);
            }
        }
        ce = ce_n; xc = xc_n; p = pn; have = have_n;
    }

    // combine 4 slices: butterfly over lanes ^1, ^2
    float* accf = (float*)acc2;
    #pragma unroll
    for (int j = 0; j < 32; j++) accf[j] += __shfl_xor(accf[j], 1, 64);
    #pragma unroll
    for (int j = 0; j < 32; j++) accf[j] += __shfl_xor(accf[j], 2, 64);

    float c_val = 0.0f;
    if (valid && slice == 0) {
        float zc = bc[0];
        zc = fmaf(xr.x, Wc[0], zc);
        zc = fmaf(xr.y, Wc[1], zc);
        zc = fmaf(xr.z, Wc[2], zc);
        zc = fmaf(xr.w, Wc[3], zc);
        #pragma unroll
        for (int j = 0; j < 32; j++) zc = fmaf(accf[j], Wc[4 + j], zc);
        c_val = softplus_f(zc + 1e-10f);
        conc[n] = c_val;

        int g = n / NN;
        int i = n - g * NN;
        if (i >= NN - NF) {
            float zm = bmu[0], zs = bsig[0];
            zm = fmaf(xr.x, Wmu[0], zm);   zs = fmaf(xr.x, Wsig[0], zs);
            zm = fmaf(xr.y, Wmu[1], zm);   zs = fmaf(xr.y, Wsig[1], zs);
            zm = fmaf(xr.z, Wmu[2], zm);   zs = fmaf(xr.z, Wsig[2], zs);
            zm = fmaf(xr.w, Wmu[3], zm);   zs = fmaf(xr.w, Wsig[3], zs);
            #pragma unroll
            for (int j = 0; j < 32; j++) {
                zm = fmaf(accf[j], Wmu[4 + j], zm);
                zs = fmaf(accf[j], Wsig[4 + j], zs);
            }
            float alpha = softplus_f(zm + 1e-20f) + 1e-20f;
            float beta  = softplus_f(zs + 1e-20f) + 1e-20f;
            int k = i - (NN - NF);
            out[(size_t)g * OUT_COLS + NN + k] = alpha / (alpha + beta) * high[k];
        }
    }

    // block reduction of c_val -> one atomic per block
    __shared__ float wave_sums[4];
    float s = c_val;
    #pragma unroll
    for (int off = 32; off > 0; off >>= 1) s += __shfl_down(s, off, 64);
    int lane = threadIdx.x & 63;
    int wid  = threadIdx.x >> 6;
    if (lane == 0) wave_sums[wid] = s;
    __syncthreads();
    if (threadIdx.x == 0) {
        float tt = wave_sums[0] + wave_sums[1] + wave_sums[2] + wave_sums[3];
        atomicAdd(sum_out, tt);
    }
}

__global__ __launch_bounds__(256) void div_kernel(
    const float* __restrict__ conc, const float* __restrict__ sum_in,
    float* __restrict__ out)
{
    int n = blockIdx.x * 256 + threadIdx.x;
    if (n >= N_NODES) return;
    float inv = 1.0f / (*sum_in + 1e-20f);
    int g = n / NN;
    int i = n - g * NN;
    out[(size_t)g * OUT_COLS + i] = conc[n] * inv;
}

extern "C" void kernel_launch(void* const* d_in, const int* in_sizes, int n_in,
                              void* d_out, int out_size, void* d_ws, size_t ws_size,
                              hipStream_t stream)
{
    const float* x    = (const float*)d_in[0];
    const int*   ei   = (const int*)d_in[1];
    const float* ea   = (const float*)d_in[2];
    const float* high = (const float*)d_in[3];
    const float* W1   = (const float*)d_in[4];
    const float* b1   = (const float*)d_in[5];
    const float* W2   = (const float*)d_in[6];
    const float* b2   = (const float*)d_in[7];
    const float* Wc   = (const float*)d_in[8];
    const float* bc   = (const float*)d_in[9];
    const float* Wmu  = (const float*)d_in[10];
    const float* bmu  = (const float*)d_in[11];
    const float* Wsig = (const float*)d_in[12];
    const float* bsig = (const float*)d_in[13];
    float* out = (float*)d_out;

    char* ws = (char*)d_ws;
    int2*  sorted = (int2*)ws;                      // 32,000,000 B
    int*   counts = (int*)(ws + 32000000);          //  1,000,000 B
    int*   offs   = (int*)(ws + 33000000);          //  1,000,000 B
    int*   cursor = (int*)(ws + 34000000);          //  1,000,000 B
    int*   bsum   = (int*)(ws + 35000000);          //      4,096 B
    float* conc   = (float*)(ws + 35004096);        //  1,000,000 B
    float* ssum   = (float*)(ws + 36004096);        //          4 B

    hipMemsetAsync(counts, 0, 1000000, stream);
    hipMemsetAsync(ssum, 0, 4, stream);

    hist_kernel<<<(N_EDGES / 4 + 255) / 256, 256, 0, stream>>>(ei, counts);
    scan_a_kernel<<<SCAN_NBLK, 256, 0, stream>>>(counts, bsum);
    scan_b_kernel<<<1, 256, 0, stream>>>(bsum);
    scan_c_kernel<<<SCAN_NBLK, 256, 0, stream>>>(counts, bsum, offs, cursor);
    scatter_kernel<<<(N_EDGES / 4 + 255) / 256, 256, 0, stream>>>(ei, ea, cursor, sorted);
    gather_kernel<<<(N_NODES * 4 + 255) / 256, 256, 0, stream>>>(
        x, offs, counts, sorted, W1, b1, W2, b2, Wc, bc, Wmu, bmu, Wsig, bsig,
        high, conc, ssum, out);
    div_kernel<<<(N_NODES + 255) / 256, 256, 0, stream>>>(conc, ssum, out);
}

// Round 4
// 887.023 us; speedup vs baseline: 7.4612x; 1.1252x over previous
//
#include <hip/hip_runtime.h>

#define N_NODES 250000
#define N_EDGES 4000000
#define HID 32
#define NN 50
#define NF 3
#define OUT_COLS (NN + NF)   // 53
#define SCAN_TILE 2048
#define SCAN_NBLK ((N_NODES + SCAN_TILE - 1) / SCAN_TILE)  // 123

typedef float float2v __attribute__((ext_vector_type(2)));

__device__ __forceinline__ float softplus_f(float v) {
    return fmaxf(v, 0.0f) + log1pf(expf(-fabsf(v)));
}

__device__ __forceinline__ float2v pk_fma(float a, float2v b, float2v c) {
    float2v av = {a, a};
    return __builtin_elementwise_fma(av, b, c);
}

// ---- Phase 1: histogram of edge rows (4 edges/thread) ----
__global__ __launch_bounds__(256) void hist_kernel(
    const int* __restrict__ ei, int* __restrict__ counts)
{
    int t = blockIdx.x * 256 + threadIdx.x;
    if (t >= N_EDGES / 4) return;
    int4 r4 = ((const int4*)ei)[t];
    atomicAdd(&counts[r4.x], 1);
    atomicAdd(&counts[r4.y], 1);
    atomicAdd(&counts[r4.z], 1);
    atomicAdd(&counts[r4.w], 1);
}

// ---- Phase 2a: per-tile sums ----
__global__ __launch_bounds__(256) void scan_a_kernel(
    const int* __restrict__ counts, int* __restrict__ bsum)
{
    int b = blockIdx.x, t = threadIdx.x;
    int base = b * SCAN_TILE + t * 8;
    int s = 0;
    #pragma unroll
    for (int j = 0; j < 8; j++) {
        int i = base + j;
        if (i < N_NODES) s += counts[i];
    }
    __shared__ int wsum[4];
    #pragma unroll
    for (int off = 32; off > 0; off >>= 1) s += __shfl_down(s, off, 64);
    int lane = t & 63, wid = t >> 6;
    if (lane == 0) wsum[wid] = s;
    __syncthreads();
    if (t == 0) bsum[b] = wsum[0] + wsum[1] + wsum[2] + wsum[3];
}

// ---- Phase 2b: exclusive scan of tile sums (single block) ----
__global__ __launch_bounds__(256) void scan_b_kernel(int* __restrict__ bsum)
{
    int t = threadIdx.x;
    __shared__ int sh[256];
    int v = (t < SCAN_NBLK) ? bsum[t] : 0;
    sh[t] = v;
    __syncthreads();
    #pragma unroll
    for (int off = 1; off < 256; off <<= 1) {
        int a = (t >= off) ? sh[t - off] : 0;
        __syncthreads();
        sh[t] += a;
        __syncthreads();
    }
    if (t < SCAN_NBLK) bsum[t] = sh[t] - v;   // exclusive
}

// ---- Phase 2c: full exclusive scan -> offs, cursor ----
__global__ __launch_bounds__(256) void scan_c_kernel(
    const int* __restrict__ counts, const int* __restrict__ bsum,
    int* __restrict__ offs, int* __restrict__ cursor)
{
    int b = blockIdx.x, t = threadIdx.x;
    int base = b * SCAN_TILE + t * 8;
    int cnt[8];
    int s = 0;
    #pragma unroll
    for (int j = 0; j < 8; j++) {
        int i = base + j;
        cnt[j] = (i < N_NODES) ? counts[i] : 0;
        s += cnt[j];
    }
    __shared__ int sh[256];
    sh[t] = s;
    __syncthreads();
    #pragma unroll
    for (int off = 1; off < 256; off <<= 1) {
        int a = (t >= off) ? sh[t - off] : 0;
        __syncthreads();
        sh[t] += a;
        __syncthreads();
    }
    int running = bsum[b] + (sh[t] - s);
    #pragma unroll
    for (int j = 0; j < 8; j++) {
        int i = base + j;
        if (i < N_NODES) {
            offs[i] = running;
            cursor[i] = running;
            running += cnt[j];
        }
    }
}

// ---- Phase 3: scatter (col, edge_attr) into CSR order (4 edges/thread) ----
__global__ __launch_bounds__(256) void scatter_kernel(
    const int* __restrict__ ei, const float* __restrict__ ea,
    int* __restrict__ cursor, int2* __restrict__ sorted)
{
    int t = blockIdx.x * 256 + threadIdx.x;
    if (t >= N_EDGES / 4) return;
    int4 r4 = ((const int4*)ei)[t];
    int4 c4 = ((const int4*)(ei + N_EDGES))[t];
    float4 e4 = ((const float4*)ea)[t];
    int pos;
    pos = atomicAdd(&cursor[r4.x], 1); sorted[pos] = make_int2(c4.x, __float_as_int(e4.x));
    pos = atomicAdd(&cursor[r4.y], 1); sorted[pos] = make_int2(c4.y, __float_as_int(e4.y));
    pos = atomicAdd(&cursor[r4.z], 1); sorted[pos] = make_int2(c4.z, __float_as_int(e4.z));
    pos = atomicAdd(&cursor[r4.w], 1); sorted[pos] = make_int2(c4.w, __float_as_int(e4.w));
}

// ---- Phase 4: gather, 1 lane/node, 4-edge chunks (weights amortized) ----
__global__ __launch_bounds__(256) void gather_kernel(
    const float* __restrict__ x, const int* __restrict__ offs,
    const int* __restrict__ counts, const int2* __restrict__ sorted,
    const float* __restrict__ W1, const float* __restrict__ b1,
    const float* __restrict__ W2, const float* __restrict__ b2,
    const float* __restrict__ Wc, const float* __restrict__ bc,
    const float* __restrict__ Wmu, const float* __restrict__ bmu,
    const float* __restrict__ Wsig, const float* __restrict__ bsig,
    const float* __restrict__ high,
    float* __restrict__ conc, float* __restrict__ sum_out,
    float* __restrict__ out)
{
    int n = blockIdx.x * 256 + threadIdx.x;
    bool valid = n < N_NODES;
    int nn = valid ? n : 0;

    int beg = offs[nn];
    int deg = valid ? counts[nn] : 0;

    float4 xr = *(const float4*)(x + 4 * (size_t)nn);

    const float2v* W1v = (const float2v*)W1;   // [9][16]
    const float2v* W2v = (const float2v*)W2;   // [32][16]
    const float2v* b1v = (const float2v*)b1;
    const float2v* b2v = (const float2v*)b2;

    float2v acc2[16];
    float fdeg = (float)deg;
    #pragma unroll
    for (int j2 = 0; j2 < 16; j2++) {
        float2v bb = b2v[j2];
        float2v z = {fdeg * bb.x, fdeg * bb.y};
        acc2[j2] = z;
    }

    for (int c = 0; c < deg; c += 4) {
        // load up to 4 edges into registers
        float mk[4], ev[4];
        float4 xc[4];
        #pragma unroll
        for (int j = 0; j < 4; j++) {
            bool ok = (c + j) < deg;
            mk[j] = ok ? 1.0f : 0.0f;
            int2 ce = ok ? sorted[beg + c + j] : make_int2(0, 0);
            ev[j] = ok ? __int_as_float(ce.y) : 0.0f;
            xc[j] = ok ? *(const float4*)(x + 4 * (size_t)ce.x)
                       : make_float4(0.f, 0.f, 0.f, 0.f);
        }
        #pragma unroll
        for (int k2 = 0; k2 < 16; k2++) {
            // weight column-pair of layer 1, loaded once for 4 edges
            float2v bb = b1v[k2];
            float2v w0 = W1v[0 * 16 + k2];
            float2v w1 = W1v[1 * 16 + k2];
            float2v w2 = W1v[2 * 16 + k2];
            float2v w3 = W1v[3 * 16 + k2];
            float2v w4 = W1v[4 * 16 + k2];
            float2v w5 = W1v[5 * 16 + k2];
            float2v w6 = W1v[6 * 16 + k2];
            float2v w7 = W1v[7 * 16 + k2];
            float2v w8 = W1v[8 * 16 + k2];
            float2v h[4];
            #pragma unroll
            for (int j = 0; j < 4; j++) {
                float2v a = bb;
                a = pk_fma(xr.x,    w0, a);
                a = pk_fma(xr.y,    w1, a);
                a = pk_fma(xr.z,    w2, a);
                a = pk_fma(xr.w,    w3, a);
                a = pk_fma(xc[j].x, w4, a);
                a = pk_fma(xc[j].y, w5, a);
                a = pk_fma(xc[j].z, w6, a);
                a = pk_fma(xc[j].w, w7, a);
                a = pk_fma(ev[j],   w8, a);
                float2v zero = {0.0f, 0.0f};
                a = __builtin_elementwise_max(a, zero);
                float2v mm = {mk[j], mk[j]};
                h[j] = a * mm;     // mask invalid slots to exactly 0
            }
            // layer-2 row pair (rows 2k2, 2k2+1), loaded once for 4 edges
            #pragma unroll
            for (int j2 = 0; j2 < 16; j2++) {
                float2v r0 = W2v[(2 * k2) * 16 + j2];
                float2v r1 = W2v[(2 * k2 + 1) * 16 + j2];
                #pragma unroll
                for (int j = 0; j < 4; j++) {
                    acc2[j2] = pk_fma(h[j].x, r0, acc2[j2]);
                    acc2[j2] = pk_fma(h[j].y, r1, acc2[j2]);
                }
            }
        }
    }

    float* accf = (float*)acc2;
    float c_val = 0.0f;
    if (valid) {
        float zc = bc[0];
        zc = fmaf(xr.x, Wc[0], zc);
        zc = fmaf(xr.y, Wc[1], zc);
        zc = fmaf(xr.z, Wc[2], zc);
        zc = fmaf(xr.w, Wc[3], zc);
        #pragma unroll
        for (int j = 0; j < 32; j++) zc = fmaf(accf[j], Wc[4 + j], zc);
        c_val = softplus_f(zc + 1e-10f);
        conc[n] = c_val;

        int g = n / NN;
        int i = n - g * NN;
        if (i >= NN - NF) {
            float zm = bmu[0], zs = bsig[0];
            zm = fmaf(xr.x, Wmu[0], zm);   zs = fmaf(xr.x, Wsig[0], zs);
            zm = fmaf(xr.y, Wmu[1], zm);   zs = fmaf(xr.y, Wsig[1], zs);
            zm = fmaf(xr.z, Wmu[2], zm);   zs = fmaf(xr.z, Wsig[2], zs);
            zm = fmaf(xr.w, Wmu[3], zm);   zs = fmaf(xr.w, Wsig[3], zs);
            #pragma unroll
            for (int j = 0; j < 32; j++) {
                zm = fmaf(accf[j], Wmu[4 + j], zm);
                zs = fmaf(accf[j], Wsig[4 + j], zs);
            }
            float alpha = softplus_f(zm + 1e-20f) + 1e-20f;
            float beta  = softplus_f(zs + 1e-20f) + 1e-20f;
            int k = i - (NN - NF);
            out[(size_t)g * OUT_COLS + NN + k] = alpha / (alpha + beta) * high[k];
        }
    }

    // block reduction of c_val -> one atomic per block
    __shared__ float wave_sums[4];
    float s = c_val;
    #pragma unroll
    for (int off = 32; off > 0; off >>= 1) s += __shfl_down(s, off, 64);
    int lane = threadIdx.x & 63;
    int wid  = threadIdx.x >> 6;
    if (lane == 0) wave_sums[wid] = s;
    __syncthreads();
    if (threadIdx.x == 0) {
        float tt = wave_sums[0] + wave_sums[1] + wave_sums[2] + wave_sums[3];
        atomicAdd(sum_out, tt);
    }
}

__global__ __launch_bounds__(256) void div_kernel(
    const float* __restrict__ conc, const float* __restrict__ sum_in,
    float* __restrict__ out)
{
    int n = blockIdx.x * 256 + threadIdx.x;
    if (n >= N_NODES) return;
    float inv = 1.0f / (*sum_in + 1e-20f);
    int g = n / NN;
    int i = n - g * NN;
    out[(size_t)g * OUT_COLS + i] = conc[n] * inv;
}

extern "C" void kernel_launch(void* const* d_in, const int* in_sizes, int n_in,
                              void* d_out, int out_size, void* d_ws, size_t ws_size,
                              hipStream_t stream)
{
    const float* x    = (const float*)d_in[0];
    const int*   ei   = (const int*)d_in[1];
    const float* ea   = (const float*)d_in[2];
    const float* high = (const float*)d_in[3];
    const float* W1   = (const float*)d_in[4];
    const float* b1   = (const float*)d_in[5];
    const float* W2   = (const float*)d_in[6];
    const float* b2   = (const float*)d_in[7];
    const float* Wc   = (const float*)d_in[8];
    const float* bc   = (const float*)d_in[9];
    const float* Wmu  = (const float*)d_in[10];
    const float* bmu  = (const float*)d_in[11];
    const float* Wsig = (const float*)d_in[12];
    const float* bsig = (const float*)d_in[13];
    float* out = (float*)d_out;

    char* ws = (char*)d_ws;
    int2*  sorted = (int2*)ws;                      // 32,000,000 B
    int*   counts = (int*)(ws + 32000000);          //  1,000,000 B
    int*   offs   = (int*)(ws + 33000000);          //  1,000,000 B
    int*   cursor = (int*)(ws + 34000000);          //  1,000,000 B
    int*   bsum   = (int*)(ws + 35000000);          //      4,096 B
    float* conc   = (float*)(ws + 35004096);        //  1,000,000 B
    float* ssum   = (float*)(ws + 36004096);        //          4 B

    hipMemsetAsync(counts, 0, 1000000, stream);
    hipMemsetAsync(ssum, 0, 4, stream);

    hist_kernel<<<(N_EDGES / 4 + 255) / 256, 256, 0, stream>>>(ei, counts);
    scan_a_kernel<<<SCAN_NBLK, 256, 0, stream>>>(counts, bsum);
    scan_b_kernel<<<1, 256, 0, stream>>>(bsum);
    scan_c_kernel<<<SCAN_NBLK, 256, 0, stream>>>(counts, bsum, offs, cursor);
    scatter_kernel<<<(N_EDGES / 4 + 255) / 256, 256, 0, stream>>>(ei, ea, cursor, sorted);
    gather_kernel<<<(N_NODES + 255) / 256, 256, 0, stream>>>(
        x, offs, counts, sorted, W1, b1, W2, b2, Wc, bc, Wmu, bmu, Wsig, bsig,
        high, conc, ssum, out);
    div_kernel<<<(N_NODES + 255) / 256, 256, 0, stream>>>(conc, ssum, out);
}